// Round 12
// baseline (329.933 us; speedup 1.0000x reference)
//
#include <hip/hip_runtime.h>
#include <math.h>

#define NN 100000
#define NE 1600000
#define SBN 512                      // nodes per super-bucket
#define NSB ((NN + SBN - 1) / SBN)   // 196 super-buckets
#define SBCAP 10240                  // per-super-bucket edge capacity (mean 8192)
#define EPB 8192                     // edges per binA block
#define NBA ((NE + EPB - 1) / EPB)   // 196 binA blocks

typedef __attribute__((ext_vector_type(8))) short bf16x8;   // 8 bf16 = 4 VGPR (MFMA A/B frag)
typedef __attribute__((ext_vector_type(8))) unsigned short ush8;
typedef __attribute__((ext_vector_type(4))) float f32x4;    // MFMA C/D frag

static __device__ __forceinline__ float b2f(unsigned short u) {
    return __uint_as_float(((unsigned int)u) << 16);
}
static __device__ __forceinline__ unsigned short f2bf(float f) {
    unsigned int u = __float_as_uint(f);
    u += 0x7fffu + ((u >> 16) & 1u);   // RNE
    return (unsigned short)(u >> 16);
}

// ---------------- conversions ----------------
__global__ __launch_bounds__(256)
void k_cvt_x(const float* __restrict__ in, unsigned short* __restrict__ outb, long total8) {
    long i = (long)blockIdx.x * 256 + threadIdx.x;
    long stride = (long)gridDim.x * 256;
    for (; i < total8; i += stride) {
        const float4* p = (const float4*)(in + i * 8);
        float4 a = p[0], b = p[1];
        ush8 r;
        r[0] = f2bf(a.x); r[1] = f2bf(a.y); r[2] = f2bf(a.z); r[3] = f2bf(a.w);
        r[4] = f2bf(b.x); r[5] = f2bf(b.y); r[6] = f2bf(b.z); r[7] = f2bf(b.w);
        *(ush8*)(outb + i * 8) = r;
    }
}

// W [128, N] f32 -> Wt [N, 128] bf16 (row-major over n)
__global__ __launch_bounds__(256)
void k_cvt_w(const float* __restrict__ W, unsigned short* __restrict__ Wt, int N) {
    int id = blockIdx.x * 256 + threadIdx.x;
    if (id < N * 128) {
        int n = id >> 7, k = id & 127;
        Wt[id] = f2bf(W[k * N + n]);
    }
}

// Wtcat[n][k]: n<64 -> W2l[k][n], else W2r[k][n-64]   (both [128,64] f32)
__global__ __launch_bounds__(256)
void k_cvt_wcat(const float* __restrict__ W2l, const float* __restrict__ W2r,
                unsigned short* __restrict__ Wt) {
    int id = blockIdx.x * 256 + threadIdx.x;
    if (id < 128 * 128) {
        int n = id >> 7, k = id & 127;
        float v = (n < 64) ? W2l[k * 64 + n] : W2r[k * 64 + (n - 64)];
        Wt[id] = f2bf(v);
    }
}

// ---------------- pass A: LDS-binned counting sort into 196 super-buckets ----------------
__global__ __launch_bounds__(1024)
void k_binA(const int* __restrict__ src, const int* __restrict__ dst,
            int* __restrict__ gcnt, int* __restrict__ pairs) {
    __shared__ int lsort[EPB];        // 32 KB
    __shared__ int lhist[256];
    __shared__ int lofs[256];         // exclusive offsets (immutable copy)
    __shared__ int lpos[NSB];
    __shared__ int gbase[NSB];
    const int tid = threadIdx.x;
    const int base = blockIdx.x * EPB;
    const int cnt = min(EPB, NE - base);

    int v[8], bn[8];
    #pragma unroll
    for (int k = 0; k < 8; ++k) {
        int i = k * 1024 + tid;
        if (i < cnt) {
            int d = dst[base + i], s = src[base + i];
            v[k] = (s << 9) | (d & 511);
            bn[k] = d >> 9;
        } else bn[k] = -1;
    }
    if (tid < 256) lhist[tid] = 0;
    __syncthreads();
    #pragma unroll
    for (int k = 0; k < 8; ++k) if (bn[k] >= 0) atomicAdd(&lhist[bn[k]], 1);
    __syncthreads();
    if (tid < 256) lofs[tid] = lhist[tid];
    __syncthreads();
    for (int d = 1; d < 256; d <<= 1) {
        int u = (tid < 256 && tid >= d) ? lofs[tid - d] : 0;
        __syncthreads();
        if (tid < 256) lofs[tid] += u;
        __syncthreads();
    }
    if (tid < 256) lofs[tid] -= lhist[tid];   // inclusive -> exclusive
    __syncthreads();
    if (tid < NSB) {
        lpos[tid] = lofs[tid];
        gbase[tid] = atomicAdd(&gcnt[tid], lhist[tid]);
    }
    __syncthreads();
    #pragma unroll
    for (int k = 0; k < 8; ++k) if (bn[k] >= 0) {
        int slot = atomicAdd(&lpos[bn[k]], 1);
        lsort[slot] = v[k];
    }
    __syncthreads();
    for (int i = tid; i < cnt; i += 1024) {
        int lo = 0, hi = NSB - 1;
        while (lo < hi) { int mid = (lo + hi + 1) >> 1; if (lofs[mid] <= i) lo = mid; else hi = mid - 1; }
        int off = gbase[lo] + (i - lofs[lo]);
        if (off < SBCAP)
            __builtin_nontemporal_store(lsort[i], &pairs[(size_t)lo * SBCAP + off]);
    }
}

// ---------------- pass B: per-super-bucket sort -> CSR (in place), deg/offs ----------------
__global__ __launch_bounds__(1024)
void k_sortB(const int* __restrict__ gcnt, int* __restrict__ pairs,
             int* __restrict__ offs, int* __restrict__ deg) {
    __shared__ int lstage[SBCAP];     // 40 KB
    __shared__ int lhist[SBN], lscan[SBN], lpos[SBN];
    const int sb = blockIdx.x, tid = threadIdx.x;
    const int cnt = min(gcnt[sb], SBCAP);
    int* __restrict__ region = pairs + (size_t)sb * SBCAP;

    for (int i = tid; i < cnt; i += 1024) lstage[i] = region[i];
    if (tid < SBN) lhist[tid] = 0;
    __syncthreads();
    for (int i = tid; i < cnt; i += 1024) atomicAdd(&lhist[lstage[i] & 511], 1);
    __syncthreads();
    if (tid < SBN) lscan[tid] = lhist[tid];
    __syncthreads();
    for (int d = 1; d < SBN; d <<= 1) {
        int u = (tid < SBN && tid >= d) ? lscan[tid - d] : 0;
        __syncthreads();
        if (tid < SBN) lscan[tid] += u;
        __syncthreads();
    }
    if (tid < SBN) {
        int ex = lscan[tid] - lhist[tid];
        lpos[tid] = ex;
        int node = sb * SBN + tid;
        if (node < NN) { offs[node] = sb * SBCAP + ex; deg[node] = lhist[tid]; }
    }
    __syncthreads();
    for (int i = tid; i < cnt; i += 1024) {
        int val = lstage[i];
        int slot = atomicAdd(&lpos[val & 511], 1);
        region[slot] = val >> 9;
    }
}

// ---------------- fused layer 1: gather-mean into LDS + dual MFMA GEMM ----------------
// Block = 128 nodes, 4 waves. Phase 1: each wave gathers means for its 32 nodes
// into a 32 KB LDS plane (bf16, XOR-swizzled 16B slots). Phase 2: dual GEMM
// hb = relu(mean@W1l + x@W1r + b1), A(s=0) from LDS, A(s=1) from global xb,
// B-frags direct from the L1-resident Wt matrices. No staging barriers.
__global__ __launch_bounds__(256)
void k_fused1(const unsigned short* __restrict__ xb, const int* __restrict__ csr,
              const int* __restrict__ offs, const int* __restrict__ deg,
              const unsigned short* __restrict__ Wtl, const unsigned short* __restrict__ Wtr,
              const float* __restrict__ bias, unsigned short* __restrict__ hb) {
    __shared__ short meanL[128 * 128];   // 32 KB; row r, 16B slot s at [r*128 + (s^(r&7))*8]

    const int tid = threadIdx.x;
    const int wave = tid >> 6, lane = tid & 63;
    const int row0 = blockIdx.x * 128;

    // ---- phase 1: gather-mean (proven k_aggregate_bf inner loop, LDS output) ----
    {
        const int q = lane >> 4, l4 = lane & 15;
        const ush8* __restrict__ f8 = (const ush8*)xb;
        for (int nl = wave; nl < 128; nl += 4) {
            int node = row0 + nl;
            float acc[8];
            #pragma unroll
            for (int i = 0; i < 8; ++i) acc[i] = 0.f;
            int dg = 0;
            if (node < NN) {
                int off = __builtin_amdgcn_readfirstlane(offs[node]);
                dg = __builtin_amdgcn_readfirstlane(deg[node]);
                int j = 0;
                for (; j + 8 <= dg; j += 8) {
                    int e0 = csr[off + j + q];
                    int e1 = csr[off + j + 4 + q];
                    ush8 v0 = f8[(size_t)e0 * 16 + l4];
                    ush8 v1 = f8[(size_t)e1 * 16 + l4];
                    #pragma unroll
                    for (int i = 0; i < 8; ++i) acc[i] += b2f(v0[i]) + b2f(v1[i]);
                }
                for (; j + 4 <= dg; j += 4) {
                    int e0 = csr[off + j + q];
                    ush8 v0 = f8[(size_t)e0 * 16 + l4];
                    #pragma unroll
                    for (int i = 0; i < 8; ++i) acc[i] += b2f(v0[i]);
                }
                int rem = dg - j;
                if (q < rem) {
                    int e0 = csr[off + j + q];
                    ush8 v0 = f8[(size_t)e0 * 16 + l4];
                    #pragma unroll
                    for (int i = 0; i < 8; ++i) acc[i] += b2f(v0[i]);
                }
                #pragma unroll
                for (int i = 0; i < 8; ++i) {
                    acc[i] += __shfl_xor(acc[i], 16);
                    acc[i] += __shfl_xor(acc[i], 32);
                }
            }
            if (q == 0) {
                float inv = 1.0f / (float)(dg > 0 ? dg : 1);
                ush8 r;
                #pragma unroll
                for (int i = 0; i < 8; ++i) r[i] = f2bf(acc[i] * inv);
                *(ush8*)&meanL[nl * 128 + (l4 ^ (nl & 7)) * 8] = r;
            }
        }
    }
    __syncthreads();

    // ---- phase 2: dual GEMM ----
    constexpr int MR = 4, NR = 4;
    const int l15 = lane & 15, kg = lane >> 4;
    const int wc = wave % 2, wr = wave / 2;
    const int rowbase = wr * 64;
    const int colbase = wc * 64;

    f32x4 acc[MR][NR];
    #pragma unroll
    for (int mr = 0; mr < MR; ++mr)
        #pragma unroll
        for (int nr = 0; nr < NR; ++nr) acc[mr][nr] = (f32x4){0.f, 0.f, 0.f, 0.f};

    for (int s = 0; s < 2; ++s) {
        const unsigned short* __restrict__ Wt = s ? Wtr : Wtl;
        #pragma unroll
        for (int kc = 0; kc < 128; kc += 32) {
            bf16x8 af[MR], bfr[NR];
            #pragma unroll
            for (int mr = 0; mr < MR; ++mr) {
                int rl = rowbase + mr * 16 + l15;
                if (s == 0) {
                    int slot = (kc >> 3) + kg;
                    af[mr] = *(const bf16x8*)&meanL[rl * 128 + (slot ^ (rl & 7)) * 8];
                } else {
                    int grow = row0 + rl;
                    if (grow >= NN) grow = NN - 1;   // clamp: stays in-bounds, result unused
                    af[mr] = *(const bf16x8*)&xb[(size_t)grow * 128 + kc + kg * 8];
                }
            }
            #pragma unroll
            for (int nr = 0; nr < NR; ++nr)
                bfr[nr] = *(const bf16x8*)&Wt[(size_t)(colbase + nr * 16 + l15) * 128 + kc + kg * 8];
            #pragma unroll
            for (int mr = 0; mr < MR; ++mr)
                #pragma unroll
                for (int nr = 0; nr < NR; ++nr)
                    acc[mr][nr] = __builtin_amdgcn_mfma_f32_16x16x32_bf16(
                        af[mr], bfr[nr], acc[mr][nr], 0, 0, 0);
        }
    }
    const int r4 = kg * 4;
    #pragma unroll
    for (int mr = 0; mr < MR; ++mr) {
        #pragma unroll
        for (int nr = 0; nr < NR; ++nr) {
            int col = colbase + nr * 16 + l15;
            float bv = bias[col];
            #pragma unroll
            for (int j = 0; j < 4; ++j) {
                int row = row0 + rowbase + mr * 16 + r4 + j;
                if (row < NN) {
                    float v = fmaxf(acc[mr][nr][j] + bv, 0.f);
                    hb[(size_t)row * 128 + col] = f2bf(v);
                }
            }
        }
    }
}

// ---------------- cat GEMM (layer 2): g = hb@W2l (bf16), z = hb@W2r + b2 (bf16) ----------------
__global__ __launch_bounds__(256)
void k_gemm_cat(const unsigned short* __restrict__ A, const unsigned short* __restrict__ Wt,
                const float* __restrict__ b2,
                unsigned short* __restrict__ g, unsigned short* __restrict__ z) {
    constexpr int BM = 128, BN = 128, MR = 4, NR = 4;
    __shared__ __align__(16) short As[BM * 40];
    __shared__ __align__(16) short Ws[BN * 40];

    const int tid = threadIdx.x;
    const int wave = tid >> 6, lane = tid & 63;
    const int l15 = lane & 15, kg = lane >> 4;
    const int wc = wave % 2, wr = wave / 2;
    const int rowbase = wr * MR * 16;
    const int colbase = wc * 64;
    const int row0 = blockIdx.x * BM;

    f32x4 acc[MR][NR];
    #pragma unroll
    for (int mr = 0; mr < MR; ++mr)
        #pragma unroll
        for (int nr = 0; nr < NR; ++nr) acc[mr][nr] = (f32x4){0.f, 0.f, 0.f, 0.f};

    for (int kc = 0; kc < 128; kc += 32) {
        __syncthreads();
        #pragma unroll
        for (int i = 0; i < 2; ++i) {
            int c = tid + 256 * i; int r = c >> 2, gg = c & 3;
            ush8 v = {0, 0, 0, 0, 0, 0, 0, 0};
            int grow = row0 + r;
            if (grow < NN) v = *(const ush8*)&A[(size_t)grow * 128 + kc + gg * 8];
            *(ush8*)&As[r * 40 + gg * 8] = v;
        }
        #pragma unroll
        for (int i = 0; i < 2; ++i) {
            int c = tid + 256 * i; int n = c >> 2, gg = c & 3;
            *(ush8*)&Ws[n * 40 + gg * 8] = *(const ush8*)&Wt[n * 128 + kc + gg * 8];
        }
        __syncthreads();
        bf16x8 af[MR], bfr[NR];
        #pragma unroll
        for (int mr = 0; mr < MR; ++mr)
            af[mr] = *(const bf16x8*)&As[(rowbase + mr * 16 + l15) * 40 + kg * 8];
        #pragma unroll
        for (int nr = 0; nr < NR; ++nr)
            bfr[nr] = *(const bf16x8*)&Ws[(colbase + nr * 16 + l15) * 40 + kg * 8];
        #pragma unroll
        for (int mr = 0; mr < MR; ++mr)
            #pragma unroll
            for (int nr = 0; nr < NR; ++nr)
                acc[mr][nr] = __builtin_amdgcn_mfma_f32_16x16x32_bf16(
                    af[mr], bfr[nr], acc[mr][nr], 0, 0, 0);
    }
    const int r4 = kg * 4;
    #pragma unroll
    for (int mr = 0; mr < MR; ++mr) {
        #pragma unroll
        for (int nr = 0; nr < NR; ++nr) {
            int col = colbase + nr * 16 + l15;
            float bv = (col >= 64) ? b2[col - 64] : 0.f;
            #pragma unroll
            for (int j = 0; j < 4; ++j) {
                int row = row0 + rowbase + mr * 16 + r4 + j;
                if (row < NN) {
                    float v = acc[mr][nr][j] + bv;
                    unsigned short bv16 = f2bf(v);
                    if (col < 64) g[(size_t)row * 64 + col] = bv16;
                    else          z[(size_t)row * 64 + (col - 64)] = bv16;
                }
            }
        }
    }
}

// ---------------- fused layer-2 tail: out = log_softmax(mean(g) + z) ----------------
// One wave per node; rows of g are 64 bf16 = 128B = 8 lanes x 16B -> 8 edges/instr.
__global__ __launch_bounds__(256)
void k_agg_lsm(const unsigned short* __restrict__ gbuf, const unsigned short* __restrict__ zbuf,
               const int* __restrict__ csr, const int* __restrict__ offs,
               const int* __restrict__ deg, float* __restrict__ out) {
    const int wid = threadIdx.x >> 6, lane = threadIdx.x & 63;
    const int g8 = lane >> 3, l8 = lane & 7;
    const int node = blockIdx.x * 4 + wid;
    if (node >= NN) return;
    int off = __builtin_amdgcn_readfirstlane(offs[node]);
    int dg  = __builtin_amdgcn_readfirstlane(deg[node]);
    const ush8* __restrict__ f8 = (const ush8*)gbuf;
    float acc[8];
    #pragma unroll
    for (int i = 0; i < 8; ++i) acc[i] = 0.f;
    int j = 0;
    for (; j + 16 <= dg; j += 16) {
        int e0 = csr[off + j + g8];
        int e1 = csr[off + j + 8 + g8];
        ush8 v0 = f8[(size_t)e0 * 8 + l8];
        ush8 v1 = f8[(size_t)e1 * 8 + l8];
        #pragma unroll
        for (int i = 0; i < 8; ++i) acc[i] += b2f(v0[i]) + b2f(v1[i]);
    }
    for (; j + 8 <= dg; j += 8) {
        int e0 = csr[off + j + g8];
        ush8 v0 = f8[(size_t)e0 * 8 + l8];
        #pragma unroll
        for (int i = 0; i < 8; ++i) acc[i] += b2f(v0[i]);
    }
    int rem = dg - j;
    if (g8 < rem) {
        int e0 = csr[off + j + g8];
        ush8 v0 = f8[(size_t)e0 * 8 + l8];
        #pragma unroll
        for (int i = 0; i < 8; ++i) acc[i] += b2f(v0[i]);
    }
    #pragma unroll
    for (int i = 0; i < 8; ++i) {
        acc[i] += __shfl_xor(acc[i], 8);
        acc[i] += __shfl_xor(acc[i], 16);
        acc[i] += __shfl_xor(acc[i], 32);
    }
    float inv = 1.0f / (float)(dg > 0 ? dg : 1);
    ush8 zv = ((const ush8*)zbuf)[(size_t)node * 8 + l8];
    float v[8];
    float m = -1e30f;
    #pragma unroll
    for (int i = 0; i < 8; ++i) {
        v[i] = acc[i] * inv + b2f(zv[i]);
        m = fmaxf(m, v[i]);
    }
    #pragma unroll
    for (int d = 4; d >= 1; d >>= 1) m = fmaxf(m, __shfl_xor(m, d));
    float ss = 0.f;
    #pragma unroll
    for (int i = 0; i < 8; ++i) ss += __expf(v[i] - m);
    #pragma unroll
    for (int d = 4; d >= 1; d >>= 1) ss += __shfl_xor(ss, d);
    float lse = m + logf(ss);
    if (g8 == 0) {
        float4 o0 = make_float4(v[0] - lse, v[1] - lse, v[2] - lse, v[3] - lse);
        float4 o1 = make_float4(v[4] - lse, v[5] - lse, v[6] - lse, v[7] - lse);
        *(float4*)&out[(size_t)node * 64 + l8 * 8]     = o0;
        *(float4*)&out[(size_t)node * 64 + l8 * 8 + 4] = o1;
    }
}

// ---------------- launch ----------------
extern "C" void kernel_launch(void* const* d_in, const int* in_sizes, int n_in,
                              void* d_out, int out_size, void* d_ws, size_t ws_size,
                              hipStream_t stream) {
    const float* x   = (const float*)d_in[0];
    const int* edges = (const int*)d_in[1];
    const float* W1l = (const float*)d_in[2];
    const float* b1  = (const float*)d_in[3];
    const float* W1r = (const float*)d_in[4];
    const float* W2l = (const float*)d_in[5];
    const float* b2  = (const float*)d_in[6];
    const float* W2r = (const float*)d_in[7];
    float* out = (float*)d_out;

    const int* src = edges;            // edge_index[0]
    const int* dst = edges + NE;       // edge_index[1]

    char* ws = (char*)d_ws;
    size_t o = 0;
    auto alloc = [&](size_t bytes) -> void* {
        void* p = ws + o;
        o = (o + bytes + 255) & ~(size_t)255;
        return p;
    };
    int* gcnt  = (int*)alloc((size_t)NSB * 4);
    int* pairs = (int*)alloc((size_t)NSB * SBCAP * 4);   // becomes CSR after sortB
    int* offs  = (int*)alloc((size_t)NN * 4);
    int* deg   = (int*)alloc((size_t)NN * 4);
    unsigned short* xb    = (unsigned short*)alloc((size_t)NN * 128 * 2);
    unsigned short* hb    = (unsigned short*)alloc((size_t)NN * 128 * 2);
    unsigned short* gbuf  = (unsigned short*)alloc((size_t)NN * 64 * 2);
    unsigned short* zbuf  = (unsigned short*)alloc((size_t)NN * 64 * 2);
    unsigned short* Wt1l  = (unsigned short*)alloc(128 * 128 * 2);
    unsigned short* Wt1r  = (unsigned short*)alloc(128 * 128 * 2);
    unsigned short* Wtcat = (unsigned short*)alloc(128 * 128 * 2);

    hipMemsetAsync(gcnt, 0, (size_t)NSB * 4, stream);

    // conversions
    k_cvt_x<<<2048, 256, 0, stream>>>(x, xb, (long)NN * 128 / 8);
    k_cvt_w<<<(128 * 128 + 255) / 256, 256, 0, stream>>>(W1l, Wt1l, 128);
    k_cvt_w<<<(128 * 128 + 255) / 256, 256, 0, stream>>>(W1r, Wt1r, 128);
    k_cvt_wcat<<<(128 * 128 + 255) / 256, 256, 0, stream>>>(W2l, W2r, Wtcat);

    // CSR build: two-level LDS counting sort
    k_binA<<<NBA, 1024, 0, stream>>>(src, dst, gcnt, pairs);
    k_sortB<<<NSB, 1024, 0, stream>>>(gcnt, pairs, offs, deg);

    const int GEMM_GRID = (NN + 127) / 128;   // 782
    // layer 1: fused gather-mean + dual GEMM
    k_fused1<<<GEMM_GRID, 256, 0, stream>>>(xb, pairs, offs, deg, Wt1l, Wt1r, b1, hb);
    // layer 2: g = h@W2l, z = h@W2r + b2, then fused 64-wide mean + add + log_softmax
    k_gemm_cat<<<GEMM_GRID, 256, 0, stream>>>(hb, Wtcat, b2, gbuf, zbuf);
    k_agg_lsm<<<(NN + 3) / 4, 256, 0, stream>>>(gbuf, zbuf, pairs, offs, deg, out);
}

// Round 13
// 219.640 us; speedup vs baseline: 1.5022x; 1.5022x over previous
//
#include <hip/hip_runtime.h>
#include <math.h>

#define NN 100000
#define NE 1600000
#define SBN 512                      // nodes per super-bucket
#define NSB ((NN + SBN - 1) / SBN)   // 196 super-buckets
#define SBCAP 10240                  // per-super-bucket edge capacity (mean 8192)
#define EPB 8192                     // edges per binA block
#define NBA ((NE + EPB - 1) / EPB)   // 196 binA blocks

typedef __attribute__((ext_vector_type(8))) short bf16x8;   // 8 bf16 = 4 VGPR (MFMA A/B frag)
typedef __attribute__((ext_vector_type(8))) unsigned short ush8;
typedef __attribute__((ext_vector_type(4))) float f32x4;    // MFMA C/D frag

static __device__ __forceinline__ float b2f(unsigned short u) {
    return __uint_as_float(((unsigned int)u) << 16);
}
static __device__ __forceinline__ unsigned short f2bf(float f) {
    unsigned int u = __float_as_uint(f);
    u += 0x7fffu + ((u >> 16) & 1u);   // RNE
    return (unsigned short)(u >> 16);
}

// ---------------- conversions ----------------
__global__ __launch_bounds__(256)
void k_cvt_x(const float* __restrict__ in, unsigned short* __restrict__ outb, long total8) {
    long i = (long)blockIdx.x * 256 + threadIdx.x;
    long stride = (long)gridDim.x * 256;
    for (; i < total8; i += stride) {
        const float4* p = (const float4*)(in + i * 8);
        float4 a = p[0], b = p[1];
        ush8 r;
        r[0] = f2bf(a.x); r[1] = f2bf(a.y); r[2] = f2bf(a.z); r[3] = f2bf(a.w);
        r[4] = f2bf(b.x); r[5] = f2bf(b.y); r[6] = f2bf(b.z); r[7] = f2bf(b.w);
        *(ush8*)(outb + i * 8) = r;
    }
}

// all weights in one launch:
//   seg 0: Wt1l[n][k] = W1l[k][n]   (128x128)
//   seg 1: Wt1r[n][k] = W1r[k][n]   (128x128)
//   seg 2: Wtcat[n][k] = n<64 ? W2l[k][n] : W2r[k][n-64]
__global__ __launch_bounds__(256)
void k_cvt_weights(const float* __restrict__ W1l, const float* __restrict__ W1r,
                   const float* __restrict__ W2l, const float* __restrict__ W2r,
                   unsigned short* __restrict__ Wt1l, unsigned short* __restrict__ Wt1r,
                   unsigned short* __restrict__ Wtcat) {
    int id = blockIdx.x * 256 + threadIdx.x;
    int seg = id >> 14;              // 16384 elements per segment
    int e = id & 16383;
    int n = e >> 7, k = e & 127;
    if (seg == 0)      Wt1l[e] = f2bf(W1l[k * 128 + n]);
    else if (seg == 1) Wt1r[e] = f2bf(W1r[k * 128 + n]);
    else if (seg == 2) {
        float v = (n < 64) ? W2l[k * 64 + n] : W2r[k * 64 + (n - 64)];
        Wtcat[e] = f2bf(v);
    }
}

// ---------------- pass A: LDS-binned counting sort into 196 super-buckets ----------------
__global__ __launch_bounds__(1024)
void k_binA(const int* __restrict__ src, const int* __restrict__ dst,
            int* __restrict__ gcnt, int* __restrict__ pairs) {
    __shared__ int lsort[EPB];        // 32 KB
    __shared__ int lhist[256];
    __shared__ int lofs[256];         // exclusive offsets (immutable copy)
    __shared__ int lpos[NSB];
    __shared__ int gbase[NSB];
    const int tid = threadIdx.x;
    const int base = blockIdx.x * EPB;
    const int cnt = min(EPB, NE - base);

    int v[8], bn[8];
    #pragma unroll
    for (int k = 0; k < 8; ++k) {
        int i = k * 1024 + tid;
        if (i < cnt) {
            int d = dst[base + i], s = src[base + i];
            v[k] = (s << 9) | (d & 511);
            bn[k] = d >> 9;
        } else bn[k] = -1;
    }
    if (tid < 256) lhist[tid] = 0;
    __syncthreads();
    #pragma unroll
    for (int k = 0; k < 8; ++k) if (bn[k] >= 0) atomicAdd(&lhist[bn[k]], 1);
    __syncthreads();
    if (tid < 256) lofs[tid] = lhist[tid];
    __syncthreads();
    for (int d = 1; d < 256; d <<= 1) {
        int u = (tid < 256 && tid >= d) ? lofs[tid - d] : 0;
        __syncthreads();
        if (tid < 256) lofs[tid] += u;
        __syncthreads();
    }
    if (tid < 256) lofs[tid] -= lhist[tid];   // inclusive -> exclusive
    __syncthreads();
    if (tid < NSB) {
        lpos[tid] = lofs[tid];
        gbase[tid] = atomicAdd(&gcnt[tid], lhist[tid]);
    }
    __syncthreads();
    #pragma unroll
    for (int k = 0; k < 8; ++k) if (bn[k] >= 0) {
        int slot = atomicAdd(&lpos[bn[k]], 1);
        lsort[slot] = v[k];
    }
    __syncthreads();
    for (int i = tid; i < cnt; i += 1024) {
        int lo = 0, hi = NSB - 1;
        while (lo < hi) { int mid = (lo + hi + 1) >> 1; if (lofs[mid] <= i) lo = mid; else hi = mid - 1; }
        int off = gbase[lo] + (i - lofs[lo]);
        if (off < SBCAP)
            __builtin_nontemporal_store(lsort[i], &pairs[(size_t)lo * SBCAP + off]);
    }
}

// ---------------- pass B: per-super-bucket sort -> CSR (in place), deg/offs ----------------
__global__ __launch_bounds__(1024)
void k_sortB(const int* __restrict__ gcnt, int* __restrict__ pairs,
             int* __restrict__ offs, int* __restrict__ deg) {
    __shared__ int lstage[SBCAP];     // 40 KB
    __shared__ int lhist[SBN], lscan[SBN], lpos[SBN];
    const int sb = blockIdx.x, tid = threadIdx.x;
    const int cnt = min(gcnt[sb], SBCAP);
    int* __restrict__ region = pairs + (size_t)sb * SBCAP;

    for (int i = tid; i < cnt; i += 1024) lstage[i] = region[i];
    if (tid < SBN) lhist[tid] = 0;
    __syncthreads();
    for (int i = tid; i < cnt; i += 1024) atomicAdd(&lhist[lstage[i] & 511], 1);
    __syncthreads();
    if (tid < SBN) lscan[tid] = lhist[tid];
    __syncthreads();
    for (int d = 1; d < SBN; d <<= 1) {
        int u = (tid < SBN && tid >= d) ? lscan[tid - d] : 0;
        __syncthreads();
        if (tid < SBN) lscan[tid] += u;
        __syncthreads();
    }
    if (tid < SBN) {
        int ex = lscan[tid] - lhist[tid];
        lpos[tid] = ex;
        int node = sb * SBN + tid;
        if (node < NN) { offs[node] = sb * SBCAP + ex; deg[node] = lhist[tid]; }
    }
    __syncthreads();
    for (int i = tid; i < cnt; i += 1024) {
        int val = lstage[i];
        int slot = atomicAdd(&lpos[val & 511], 1);
        region[slot] = val >> 9;
    }
}

// ---------------- bf16 mean aggregation (layer 1): one wave per node ----------------
// 16-lane groups, 1 edge/group; main loop keeps 4 rows (4 KB) in flight per wave.
__global__ __launch_bounds__(256)
void k_aggregate_bf(const unsigned short* __restrict__ feat, const int* __restrict__ csr,
                    const int* __restrict__ offs, const int* __restrict__ deg,
                    unsigned short* __restrict__ outmean) {
    const int wid = threadIdx.x >> 6, lane = threadIdx.x & 63;
    const int q = lane >> 4, l4 = lane & 15;
    const int node = blockIdx.x * 4 + wid;
    if (node >= NN) return;
    int off = __builtin_amdgcn_readfirstlane(offs[node]);
    int dg  = __builtin_amdgcn_readfirstlane(deg[node]);
    const ush8* __restrict__ f8 = (const ush8*)feat;
    float acc[8];
    #pragma unroll
    for (int i = 0; i < 8; ++i) acc[i] = 0.f;
    int j = 0;
    for (; j + 16 <= dg; j += 16) {
        int e0 = csr[off + j + q];
        int e1 = csr[off + j + 4 + q];
        int e2 = csr[off + j + 8 + q];
        int e3 = csr[off + j + 12 + q];
        ush8 v0 = f8[(size_t)e0 * 16 + l4];
        ush8 v1 = f8[(size_t)e1 * 16 + l4];
        ush8 v2 = f8[(size_t)e2 * 16 + l4];
        ush8 v3 = f8[(size_t)e3 * 16 + l4];
        #pragma unroll
        for (int i = 0; i < 8; ++i)
            acc[i] += (b2f(v0[i]) + b2f(v1[i])) + (b2f(v2[i]) + b2f(v3[i]));
    }
    for (; j + 8 <= dg; j += 8) {
        int e0 = csr[off + j + q];
        int e1 = csr[off + j + 4 + q];
        ush8 v0 = f8[(size_t)e0 * 16 + l4];
        ush8 v1 = f8[(size_t)e1 * 16 + l4];
        #pragma unroll
        for (int i = 0; i < 8; ++i) acc[i] += b2f(v0[i]) + b2f(v1[i]);
    }
    for (; j + 4 <= dg; j += 4) {
        int e0 = csr[off + j + q];
        ush8 v0 = f8[(size_t)e0 * 16 + l4];
        #pragma unroll
        for (int i = 0; i < 8; ++i) acc[i] += b2f(v0[i]);
    }
    int rem = dg - j;
    if (q < rem) {
        int e0 = csr[off + j + q];
        ush8 v0 = f8[(size_t)e0 * 16 + l4];
        #pragma unroll
        for (int i = 0; i < 8; ++i) acc[i] += b2f(v0[i]);
    }
    #pragma unroll
    for (int i = 0; i < 8; ++i) {
        acc[i] += __shfl_xor(acc[i], 16);
        acc[i] += __shfl_xor(acc[i], 32);
    }
    if (q == 0) {
        float inv = 1.0f / (float)(dg > 0 ? dg : 1);
        ush8 r;
        #pragma unroll
        for (int i = 0; i < 8; ++i) r[i] = f2bf(acc[i] * inv);
        ((ush8*)outmean)[(size_t)node * 16 + l4] = r;
    }
}

// ---------------- MFMA dual GEMM (layer 1): hb = relu(Am@Wl + Ax@Wr + b1) ----------------
template <int BN, bool RELU, bool OUTBF>
__global__ __launch_bounds__(256)
void k_gemm_mfma(const unsigned short* __restrict__ Am, const unsigned short* __restrict__ Ax,
                 const unsigned short* __restrict__ Wtl, const unsigned short* __restrict__ Wtr,
                 const float* __restrict__ bias, void* __restrict__ outp) {
    constexpr int BM = 128;
    constexpr int WAVES_N = BN / 64;
    constexpr int WAVES_M = 4 / WAVES_N;
    constexpr int MR = BM / (WAVES_M * 16);
    constexpr int NR = 4;
    __shared__ __align__(16) short As[BM * 40];
    __shared__ __align__(16) short Ws[BN * 40];

    const int tid = threadIdx.x;
    const int wave = tid >> 6, lane = tid & 63;
    const int l15 = lane & 15, kg = lane >> 4;
    const int wc = wave % WAVES_N, wr = wave / WAVES_N;
    const int rowbase = wr * MR * 16;
    const int colbase = wc * 64;
    const int row0 = blockIdx.x * BM;

    f32x4 acc[MR][NR];
    #pragma unroll
    for (int mr = 0; mr < MR; ++mr)
        #pragma unroll
        for (int nr = 0; nr < NR; ++nr) acc[mr][nr] = (f32x4){0.f, 0.f, 0.f, 0.f};

    for (int s = 0; s < 2; ++s) {
        const unsigned short* __restrict__ A  = s ? Ax : Am;
        const unsigned short* __restrict__ Wt = s ? Wtr : Wtl;
        for (int kc = 0; kc < 128; kc += 32) {
            __syncthreads();
            #pragma unroll
            for (int i = 0; i < (BM * 4) / 256; ++i) {
                int c = tid + 256 * i; int r = c >> 2, g = c & 3;
                ush8 v = {0, 0, 0, 0, 0, 0, 0, 0};
                int grow = row0 + r;
                if (grow < NN) v = *(const ush8*)&A[(size_t)grow * 128 + kc + g * 8];
                *(ush8*)&As[r * 40 + g * 8] = v;
            }
            #pragma unroll
            for (int i = 0; i < (BN * 4) / 256; ++i) {
                int c = tid + 256 * i; int n = c >> 2, g = c & 3;
                *(ush8*)&Ws[n * 40 + g * 8] = *(const ush8*)&Wt[n * 128 + kc + g * 8];
            }
            __syncthreads();
            bf16x8 af[MR], bfr[NR];
            #pragma unroll
            for (int mr = 0; mr < MR; ++mr)
                af[mr] = *(const bf16x8*)&As[(rowbase + mr * 16 + l15) * 40 + kg * 8];
            #pragma unroll
            for (int nr = 0; nr < NR; ++nr)
                bfr[nr] = *(const bf16x8*)&Ws[(colbase + nr * 16 + l15) * 40 + kg * 8];
            #pragma unroll
            for (int mr = 0; mr < MR; ++mr)
                #pragma unroll
                for (int nr = 0; nr < NR; ++nr)
                    acc[mr][nr] = __builtin_amdgcn_mfma_f32_16x16x32_bf16(
                        af[mr], bfr[nr], acc[mr][nr], 0, 0, 0);
        }
    }
    const int r4 = kg * 4;
    #pragma unroll
    for (int mr = 0; mr < MR; ++mr) {
        #pragma unroll
        for (int nr = 0; nr < NR; ++nr) {
            int col = colbase + nr * 16 + l15;
            float bv = bias[col];
            #pragma unroll
            for (int j = 0; j < 4; ++j) {
                int row = row0 + rowbase + mr * 16 + r4 + j;
                if (row < NN) {
                    float v = acc[mr][nr][j] + bv;
                    if (RELU) v = fmaxf(v, 0.f);
                    if (OUTBF) ((unsigned short*)outp)[(size_t)row * BN + col] = f2bf(v);
                    else       ((float*)outp)[(size_t)row * BN + col] = v;
                }
            }
        }
    }
}

// ---------------- cat GEMM (layer 2): g = hb@W2l (bf16), z = hb@W2r + b2 (bf16) ----------------
__global__ __launch_bounds__(256)
void k_gemm_cat(const unsigned short* __restrict__ A, const unsigned short* __restrict__ Wt,
                const float* __restrict__ b2,
                unsigned short* __restrict__ g, unsigned short* __restrict__ z) {
    constexpr int BM = 128, BN = 128, MR = 4, NR = 4;
    __shared__ __align__(16) short As[BM * 40];
    __shared__ __align__(16) short Ws[BN * 40];

    const int tid = threadIdx.x;
    const int wave = tid >> 6, lane = tid & 63;
    const int l15 = lane & 15, kg = lane >> 4;
    const int wc = wave % 2, wr = wave / 2;
    const int rowbase = wr * MR * 16;
    const int colbase = wc * 64;
    const int row0 = blockIdx.x * BM;

    f32x4 acc[MR][NR];
    #pragma unroll
    for (int mr = 0; mr < MR; ++mr)
        #pragma unroll
        for (int nr = 0; nr < NR; ++nr) acc[mr][nr] = (f32x4){0.f, 0.f, 0.f, 0.f};

    for (int kc = 0; kc < 128; kc += 32) {
        __syncthreads();
        #pragma unroll
        for (int i = 0; i < 2; ++i) {
            int c = tid + 256 * i; int r = c >> 2, gg = c & 3;
            ush8 v = {0, 0, 0, 0, 0, 0, 0, 0};
            int grow = row0 + r;
            if (grow < NN) v = *(const ush8*)&A[(size_t)grow * 128 + kc + gg * 8];
            *(ush8*)&As[r * 40 + gg * 8] = v;
        }
        #pragma unroll
        for (int i = 0; i < 2; ++i) {
            int c = tid + 256 * i; int n = c >> 2, gg = c & 3;
            *(ush8*)&Ws[n * 40 + gg * 8] = *(const ush8*)&Wt[n * 128 + kc + gg * 8];
        }
        __syncthreads();
        bf16x8 af[MR], bfr[NR];
        #pragma unroll
        for (int mr = 0; mr < MR; ++mr)
            af[mr] = *(const bf16x8*)&As[(rowbase + mr * 16 + l15) * 40 + kg * 8];
        #pragma unroll
        for (int nr = 0; nr < NR; ++nr)
            bfr[nr] = *(const bf16x8*)&Ws[(colbase + nr * 16 + l15) * 40 + kg * 8];
        #pragma unroll
        for (int mr = 0; mr < MR; ++mr)
            #pragma unroll
            for (int nr = 0; nr < NR; ++nr)
                acc[mr][nr] = __builtin_amdgcn_mfma_f32_16x16x32_bf16(
                    af[mr], bfr[nr], acc[mr][nr], 0, 0, 0);
    }
    const int r4 = kg * 4;
    #pragma unroll
    for (int mr = 0; mr < MR; ++mr) {
        #pragma unroll
        for (int nr = 0; nr < NR; ++nr) {
            int col = colbase + nr * 16 + l15;
            float bv = (col >= 64) ? b2[col - 64] : 0.f;
            #pragma unroll
            for (int j = 0; j < 4; ++j) {
                int row = row0 + rowbase + mr * 16 + r4 + j;
                if (row < NN) {
                    float v = acc[mr][nr][j] + bv;
                    unsigned short bv16 = f2bf(v);
                    if (col < 64) g[(size_t)row * 64 + col] = bv16;
                    else          z[(size_t)row * 64 + (col - 64)] = bv16;
                }
            }
        }
    }
}

// ---------------- fused layer-2 tail: out = log_softmax(mean(g) + z) ----------------
// One wave per node; g rows = 64 bf16 = 128B = 8 lanes x 16B -> 8 edges/instr,
// main loop keeps 4 rows in flight per lane-group (32 edges/iter).
__global__ __launch_bounds__(256)
void k_agg_lsm(const unsigned short* __restrict__ gbuf, const unsigned short* __restrict__ zbuf,
               const int* __restrict__ csr, const int* __restrict__ offs,
               const int* __restrict__ deg, float* __restrict__ out) {
    const int wid = threadIdx.x >> 6, lane = threadIdx.x & 63;
    const int g8 = lane >> 3, l8 = lane & 7;
    const int node = blockIdx.x * 4 + wid;
    if (node >= NN) return;
    int off = __builtin_amdgcn_readfirstlane(offs[node]);
    int dg  = __builtin_amdgcn_readfirstlane(deg[node]);
    const ush8* __restrict__ f8 = (const ush8*)gbuf;
    float acc[8];
    #pragma unroll
    for (int i = 0; i < 8; ++i) acc[i] = 0.f;
    int j = 0;
    for (; j + 32 <= dg; j += 32) {
        int e0 = csr[off + j + g8];
        int e1 = csr[off + j + 8 + g8];
        int e2 = csr[off + j + 16 + g8];
        int e3 = csr[off + j + 24 + g8];
        ush8 v0 = f8[(size_t)e0 * 8 + l8];
        ush8 v1 = f8[(size_t)e1 * 8 + l8];
        ush8 v2 = f8[(size_t)e2 * 8 + l8];
        ush8 v3 = f8[(size_t)e3 * 8 + l8];
        #pragma unroll
        for (int i = 0; i < 8; ++i)
            acc[i] += (b2f(v0[i]) + b2f(v1[i])) + (b2f(v2[i]) + b2f(v3[i]));
    }
    for (; j + 16 <= dg; j += 16) {
        int e0 = csr[off + j + g8];
        int e1 = csr[off + j + 8 + g8];
        ush8 v0 = f8[(size_t)e0 * 8 + l8];
        ush8 v1 = f8[(size_t)e1 * 8 + l8];
        #pragma unroll
        for (int i = 0; i < 8; ++i) acc[i] += b2f(v0[i]) + b2f(v1[i]);
    }
    for (; j + 8 <= dg; j += 8) {
        int e0 = csr[off + j + g8];
        ush8 v0 = f8[(size_t)e0 * 8 + l8];
        #pragma unroll
        for (int i = 0; i < 8; ++i) acc[i] += b2f(v0[i]);
    }
    int rem = dg - j;
    if (g8 < rem) {
        int e0 = csr[off + j + g8];
        ush8 v0 = f8[(size_t)e0 * 8 + l8];
        #pragma unroll
        for (int i = 0; i < 8; ++i) acc[i] += b2f(v0[i]);
    }
    #pragma unroll
    for (int i = 0; i < 8; ++i) {
        acc[i] += __shfl_xor(acc[i], 8);
        acc[i] += __shfl_xor(acc[i], 16);
        acc[i] += __shfl_xor(acc[i], 32);
    }
    float inv = 1.0f / (float)(dg > 0 ? dg : 1);
    ush8 zv = ((const ush8*)zbuf)[(size_t)node * 8 + l8];
    float v[8];
    float m = -1e30f;
    #pragma unroll
    for (int i = 0; i < 8; ++i) {
        v[i] = acc[i] * inv + b2f(zv[i]);
        m = fmaxf(m, v[i]);
    }
    #pragma unroll
    for (int d = 4; d >= 1; d >>= 1) m = fmaxf(m, __shfl_xor(m, d));
    float ss = 0.f;
    #pragma unroll
    for (int i = 0; i < 8; ++i) ss += __expf(v[i] - m);
    #pragma unroll
    for (int d = 4; d >= 1; d >>= 1) ss += __shfl_xor(ss, d);
    float lse = m + logf(ss);
    if (g8 == 0) {
        float4 o0 = make_float4(v[0] - lse, v[1] - lse, v[2] - lse, v[3] - lse);
        float4 o1 = make_float4(v[4] - lse, v[5] - lse, v[6] - lse, v[7] - lse);
        *(float4*)&out[(size_t)node * 64 + l8 * 8]     = o0;
        *(float4*)&out[(size_t)node * 64 + l8 * 8 + 4] = o1;
    }
}

// ---------------- launch ----------------
extern "C" void kernel_launch(void* const* d_in, const int* in_sizes, int n_in,
                              void* d_out, int out_size, void* d_ws, size_t ws_size,
                              hipStream_t stream) {
    const float* x   = (const float*)d_in[0];
    const int* edges = (const int*)d_in[1];
    const float* W1l = (const float*)d_in[2];
    const float* b1  = (const float*)d_in[3];
    const float* W1r = (const float*)d_in[4];
    const float* W2l = (const float*)d_in[5];
    const float* b2  = (const float*)d_in[6];
    const float* W2r = (const float*)d_in[7];
    float* out = (float*)d_out;

    const int* src = edges;            // edge_index[0]
    const int* dst = edges + NE;       // edge_index[1]

    char* ws = (char*)d_ws;
    size_t o = 0;
    auto alloc = [&](size_t bytes) -> void* {
        void* p = ws + o;
        o = (o + bytes + 255) & ~(size_t)255;
        return p;
    };
    int* gcnt  = (int*)alloc((size_t)NSB * 4);
    int* pairs = (int*)alloc((size_t)NSB * SBCAP * 4);   // becomes CSR after sortB
    int* offs  = (int*)alloc((size_t)NN * 4);
    int* deg   = (int*)alloc((size_t)NN * 4);
    unsigned short* xb    = (unsigned short*)alloc((size_t)NN * 128 * 2);
    unsigned short* meanb = (unsigned short*)alloc((size_t)NN * 128 * 2);
    unsigned short* hb    = (unsigned short*)alloc((size_t)NN * 128 * 2);
    unsigned short* gbuf  = (unsigned short*)alloc((size_t)NN * 64 * 2);
    unsigned short* zbuf  = (unsigned short*)alloc((size_t)NN * 64 * 2);
    unsigned short* Wt1l  = (unsigned short*)alloc(128 * 128 * 2);
    unsigned short* Wt1r  = (unsigned short*)alloc(128 * 128 * 2);
    unsigned short* Wtcat = (unsigned short*)alloc(128 * 128 * 2);

    hipMemsetAsync(gcnt, 0, (size_t)NSB * 4, stream);

    // conversions
    k_cvt_x<<<2048, 256, 0, stream>>>(x, xb, (long)NN * 128 / 8);
    k_cvt_weights<<<(3 * 16384 + 255) / 256, 256, 0, stream>>>(W1l, W1r, W2l, W2r,
                                                               Wt1l, Wt1r, Wtcat);

    // CSR build: two-level LDS counting sort
    k_binA<<<NBA, 1024, 0, stream>>>(src, dst, gcnt, pairs);
    k_sortB<<<NSB, 1024, 0, stream>>>(gcnt, pairs, offs, deg);

    const int GEMM_GRID = (NN + 127) / 128;   // 782
    // layer 1
    k_aggregate_bf<<<(NN + 3) / 4, 256, 0, stream>>>(xb, pairs, offs, deg, meanb);
    k_gemm_mfma<128, true, true><<<GEMM_GRID, 256, 0, stream>>>(meanb, xb, Wt1l, Wt1r, b1, hb);
    // layer 2: g = h@W2l, z = h@W2r + b2, then fused 64-wide mean + add + log_softmax
    k_gemm_cat<<<GEMM_GRID, 256, 0, stream>>>(hb, Wtcat, b2, gbuf, zbuf);
    k_agg_lsm<<<(NN + 3) / 4, 256, 0, stream>>>(gbuf, zbuf, pairs, offs, deg, out);
}

// Round 14
// 205.360 us; speedup vs baseline: 1.6066x; 1.0695x over previous
//
#include <hip/hip_runtime.h>
#include <math.h>

#define NN 100000
#define NE 1600000
#define SBN 512                      // nodes per super-bucket
#define NSB ((NN + SBN - 1) / SBN)   // 196 super-buckets
#define SBCAP 10240                  // per-super-bucket edge capacity (mean 8192)
#define EPB 8192                     // edges per binA block
#define NBA ((NE + EPB - 1) / EPB)   // 196 binA blocks

typedef __attribute__((ext_vector_type(8))) short bf16x8;   // 8 bf16 = 4 VGPR (MFMA A/B frag)
typedef __attribute__((ext_vector_type(8))) unsigned short ush8;
typedef __attribute__((ext_vector_type(4))) float f32x4;    // MFMA C/D frag

static __device__ __forceinline__ float b2f(unsigned short u) {
    return __uint_as_float(((unsigned int)u) << 16);
}
static __device__ __forceinline__ unsigned short f2bf(float f) {
    unsigned int u = __float_as_uint(f);
    u += 0x7fffu + ((u >> 16) & 1u);   // RNE
    return (unsigned short)(u >> 16);
}

// ---------------- conversions ----------------
__global__ __launch_bounds__(256)
void k_cvt_x(const float* __restrict__ in, unsigned short* __restrict__ outb, long total8) {
    long i = (long)blockIdx.x * 256 + threadIdx.x;
    long stride = (long)gridDim.x * 256;
    for (; i < total8; i += stride) {
        const float4* p = (const float4*)(in + i * 8);
        float4 a = p[0], b = p[1];
        ush8 r;
        r[0] = f2bf(a.x); r[1] = f2bf(a.y); r[2] = f2bf(a.z); r[3] = f2bf(a.w);
        r[4] = f2bf(b.x); r[5] = f2bf(b.y); r[6] = f2bf(b.z); r[7] = f2bf(b.w);
        *(ush8*)(outb + i * 8) = r;
    }
}

// all weights in one launch:
//   seg 0: Wt1l[n][k] = W1l[k][n]   (128x128)
//   seg 1: Wt1r[n][k] = W1r[k][n]   (128x128)
//   seg 2: Wtcat[n][k] = n<64 ? W2l[k][n] : W2r[k][n-64]
__global__ __launch_bounds__(256)
void k_cvt_weights(const float* __restrict__ W1l, const float* __restrict__ W1r,
                   const float* __restrict__ W2l, const float* __restrict__ W2r,
                   unsigned short* __restrict__ Wt1l, unsigned short* __restrict__ Wt1r,
                   unsigned short* __restrict__ Wtcat) {
    int id = blockIdx.x * 256 + threadIdx.x;
    int seg = id >> 14;              // 16384 elements per segment
    int e = id & 16383;
    int n = e >> 7, k = e & 127;
    if (seg == 0)      Wt1l[e] = f2bf(W1l[k * 128 + n]);
    else if (seg == 1) Wt1r[e] = f2bf(W1r[k * 128 + n]);
    else if (seg == 2) {
        float v = (n < 64) ? W2l[k * 64 + n] : W2r[k * 64 + (n - 64)];
        Wtcat[e] = f2bf(v);
    }
}

// ---------------- pass A: LDS-binned counting sort into 196 super-buckets ----------------
__global__ __launch_bounds__(1024)
void k_binA(const int* __restrict__ src, const int* __restrict__ dst,
            int* __restrict__ gcnt, int* __restrict__ pairs) {
    __shared__ int lsort[EPB];        // 32 KB
    __shared__ int lhist[256];
    __shared__ int lofs[256];         // exclusive offsets (immutable copy)
    __shared__ int lpos[NSB];
    __shared__ int gbase[NSB];
    const int tid = threadIdx.x;
    const int base = blockIdx.x * EPB;
    const int cnt = min(EPB, NE - base);

    int v[8], bn[8];
    #pragma unroll
    for (int k = 0; k < 8; ++k) {
        int i = k * 1024 + tid;
        if (i < cnt) {
            int d = dst[base + i], s = src[base + i];
            v[k] = (s << 9) | (d & 511);
            bn[k] = d >> 9;
        } else bn[k] = -1;
    }
    if (tid < 256) lhist[tid] = 0;
    __syncthreads();
    #pragma unroll
    for (int k = 0; k < 8; ++k) if (bn[k] >= 0) atomicAdd(&lhist[bn[k]], 1);
    __syncthreads();
    if (tid < 256) lofs[tid] = lhist[tid];
    __syncthreads();
    for (int d = 1; d < 256; d <<= 1) {
        int u = (tid < 256 && tid >= d) ? lofs[tid - d] : 0;
        __syncthreads();
        if (tid < 256) lofs[tid] += u;
        __syncthreads();
    }
    if (tid < 256) lofs[tid] -= lhist[tid];   // inclusive -> exclusive
    __syncthreads();
    if (tid < NSB) {
        lpos[tid] = lofs[tid];
        gbase[tid] = atomicAdd(&gcnt[tid], lhist[tid]);
    }
    __syncthreads();
    #pragma unroll
    for (int k = 0; k < 8; ++k) if (bn[k] >= 0) {
        int slot = atomicAdd(&lpos[bn[k]], 1);
        lsort[slot] = v[k];
    }
    __syncthreads();
    for (int i = tid; i < cnt; i += 1024) {
        int lo = 0, hi = NSB - 1;
        while (lo < hi) { int mid = (lo + hi + 1) >> 1; if (lofs[mid] <= i) lo = mid; else hi = mid - 1; }
        int off = gbase[lo] + (i - lofs[lo]);
        if (off < SBCAP)
            __builtin_nontemporal_store(lsort[i], &pairs[(size_t)lo * SBCAP + off]);
    }
}

// ---------------- pass B: per-super-bucket sort -> CSR (in place), deg/offs ----------------
__global__ __launch_bounds__(1024)
void k_sortB(const int* __restrict__ gcnt, int* __restrict__ pairs,
             int* __restrict__ offs, int* __restrict__ deg) {
    __shared__ int lstage[SBCAP];     // 40 KB
    __shared__ int lhist[SBN], lscan[SBN], lpos[SBN];
    const int sb = blockIdx.x, tid = threadIdx.x;
    const int cnt = min(gcnt[sb], SBCAP);
    int* __restrict__ region = pairs + (size_t)sb * SBCAP;

    for (int i = tid; i < cnt; i += 1024) lstage[i] = region[i];
    if (tid < SBN) lhist[tid] = 0;
    __syncthreads();
    for (int i = tid; i < cnt; i += 1024) atomicAdd(&lhist[lstage[i] & 511], 1);
    __syncthreads();
    if (tid < SBN) lscan[tid] = lhist[tid];
    __syncthreads();
    for (int d = 1; d < SBN; d <<= 1) {
        int u = (tid < SBN && tid >= d) ? lscan[tid - d] : 0;
        __syncthreads();
        if (tid < SBN) lscan[tid] += u;
        __syncthreads();
    }
    if (tid < SBN) {
        int ex = lscan[tid] - lhist[tid];
        lpos[tid] = ex;
        int node = sb * SBN + tid;
        if (node < NN) { offs[node] = sb * SBCAP + ex; deg[node] = lhist[tid]; }
    }
    __syncthreads();
    for (int i = tid; i < cnt; i += 1024) {
        int val = lstage[i];
        int slot = atomicAdd(&lpos[val & 511], 1);
        region[slot] = val >> 9;
    }
}

// ---------------- bf16 mean aggregation (layer 1): one wave per node ----------------
__global__ __launch_bounds__(256)
void k_aggregate_bf(const unsigned short* __restrict__ feat, const int* __restrict__ csr,
                    const int* __restrict__ offs, const int* __restrict__ deg,
                    unsigned short* __restrict__ outmean) {
    const int wid = threadIdx.x >> 6, lane = threadIdx.x & 63;
    const int q = lane >> 4, l4 = lane & 15;
    const int node = blockIdx.x * 4 + wid;
    if (node >= NN) return;
    int off = __builtin_amdgcn_readfirstlane(offs[node]);
    int dg  = __builtin_amdgcn_readfirstlane(deg[node]);
    const ush8* __restrict__ f8 = (const ush8*)feat;
    float acc[8];
    #pragma unroll
    for (int i = 0; i < 8; ++i) acc[i] = 0.f;
    int j = 0;
    for (; j + 16 <= dg; j += 16) {
        int e0 = csr[off + j + q];
        int e1 = csr[off + j + 4 + q];
        int e2 = csr[off + j + 8 + q];
        int e3 = csr[off + j + 12 + q];
        ush8 v0 = f8[(size_t)e0 * 16 + l4];
        ush8 v1 = f8[(size_t)e1 * 16 + l4];
        ush8 v2 = f8[(size_t)e2 * 16 + l4];
        ush8 v3 = f8[(size_t)e3 * 16 + l4];
        #pragma unroll
        for (int i = 0; i < 8; ++i)
            acc[i] += (b2f(v0[i]) + b2f(v1[i])) + (b2f(v2[i]) + b2f(v3[i]));
    }
    for (; j + 8 <= dg; j += 8) {
        int e0 = csr[off + j + q];
        int e1 = csr[off + j + 4 + q];
        ush8 v0 = f8[(size_t)e0 * 16 + l4];
        ush8 v1 = f8[(size_t)e1 * 16 + l4];
        #pragma unroll
        for (int i = 0; i < 8; ++i) acc[i] += b2f(v0[i]) + b2f(v1[i]);
    }
    for (; j + 4 <= dg; j += 4) {
        int e0 = csr[off + j + q];
        ush8 v0 = f8[(size_t)e0 * 16 + l4];
        #pragma unroll
        for (int i = 0; i < 8; ++i) acc[i] += b2f(v0[i]);
    }
    int rem = dg - j;
    if (q < rem) {
        int e0 = csr[off + j + q];
        ush8 v0 = f8[(size_t)e0 * 16 + l4];
        #pragma unroll
        for (int i = 0; i < 8; ++i) acc[i] += b2f(v0[i]);
    }
    #pragma unroll
    for (int i = 0; i < 8; ++i) {
        acc[i] += __shfl_xor(acc[i], 16);
        acc[i] += __shfl_xor(acc[i], 32);
    }
    if (q == 0) {
        float inv = 1.0f / (float)(dg > 0 ? dg : 1);
        ush8 r;
        #pragma unroll
        for (int i = 0; i < 8; ++i) r[i] = f2bf(acc[i] * inv);
        ((ush8*)outmean)[(size_t)node * 16 + l4] = r;
    }
}

// ---------------- fused GEMM chain: hb = relu(Am@W1l + Ax@W1r + b1) [LDS tile],
//                  then {g | z} = hb @ Wtcat (+b2 on z half). hb never hits HBM. ----------------
__global__ __launch_bounds__(256)
void k_gemm12(const unsigned short* __restrict__ Am, const unsigned short* __restrict__ Ax,
              const unsigned short* __restrict__ Wtl, const unsigned short* __restrict__ Wtr,
              const unsigned short* __restrict__ Wtcat,
              const float* __restrict__ b1, const float* __restrict__ b2,
              unsigned short* __restrict__ g, unsigned short* __restrict__ z) {
    // LDS union: phase A uses As[128*40] + Ws[128*40] (20,480 B);
    // after a barrier the same memory holds hbL[128][136] (34,816 B).
    __shared__ __align__(16) short lds[17408];
    short* As = lds;
    short* Ws = lds + 5120;
    short* hbL = lds;

    const int tid = threadIdx.x;
    const int wave = tid >> 6, lane = tid & 63;
    const int l15 = lane & 15, kg = lane >> 4;
    const int wc = wave & 1, wr = wave >> 1;
    const int rowbase = wr * 64;
    const int colbase = wc * 64;
    const int row0 = blockIdx.x * 128;
    const int r4 = kg * 4;

    f32x4 acc[4][4];
    #pragma unroll
    for (int mr = 0; mr < 4; ++mr)
        #pragma unroll
        for (int nr = 0; nr < 4; ++nr) acc[mr][nr] = (f32x4){0.f, 0.f, 0.f, 0.f};

    // ---- phase A: dual GEMM over meanb (Am) and xb (Ax) ----
    for (int s = 0; s < 2; ++s) {
        const unsigned short* __restrict__ A  = s ? Ax : Am;
        const unsigned short* __restrict__ Wt = s ? Wtr : Wtl;
        for (int kc = 0; kc < 128; kc += 32) {
            __syncthreads();
            #pragma unroll
            for (int i = 0; i < 2; ++i) {
                int c = tid + 256 * i; int r = c >> 2, gq = c & 3;
                ush8 v = {0, 0, 0, 0, 0, 0, 0, 0};
                int grow = row0 + r;
                if (grow < NN) v = *(const ush8*)&A[(size_t)grow * 128 + kc + gq * 8];
                *(ush8*)&As[r * 40 + gq * 8] = v;
            }
            #pragma unroll
            for (int i = 0; i < 2; ++i) {
                int c = tid + 256 * i; int n = c >> 2, gq = c & 3;
                *(ush8*)&Ws[n * 40 + gq * 8] = *(const ush8*)&Wt[n * 128 + kc + gq * 8];
            }
            __syncthreads();
            bf16x8 af[4], bfr[4];
            #pragma unroll
            for (int mr = 0; mr < 4; ++mr)
                af[mr] = *(const bf16x8*)&As[(rowbase + mr * 16 + l15) * 40 + kg * 8];
            #pragma unroll
            for (int nr = 0; nr < 4; ++nr)
                bfr[nr] = *(const bf16x8*)&Ws[(colbase + nr * 16 + l15) * 40 + kg * 8];
            #pragma unroll
            for (int mr = 0; mr < 4; ++mr)
                #pragma unroll
                for (int nr = 0; nr < 4; ++nr)
                    acc[mr][nr] = __builtin_amdgcn_mfma_f32_16x16x32_bf16(
                        af[mr], bfr[nr], acc[mr][nr], 0, 0, 0);
        }
    }

    // ---- write hb tile (relu + b1, bf16) into LDS union ----
    __syncthreads();   // all As/Ws reads complete before overwrite
    #pragma unroll
    for (int nr = 0; nr < 4; ++nr) {
        int col = colbase + nr * 16 + l15;
        float bv = b1[col];
        #pragma unroll
        for (int mr = 0; mr < 4; ++mr) {
            #pragma unroll
            for (int j = 0; j < 4; ++j) {
                int rl = rowbase + mr * 16 + r4 + j;
                float v = fmaxf(acc[mr][nr][j] + bv, 0.f);
                hbL[rl * 136 + col] = (short)f2bf(v);
            }
        }
    }
    __syncthreads();

    // ---- phase B: {g|z} = hbL @ Wtcat, K = 128, B direct from L1-resident global ----
    #pragma unroll
    for (int mr = 0; mr < 4; ++mr)
        #pragma unroll
        for (int nr = 0; nr < 4; ++nr) acc[mr][nr] = (f32x4){0.f, 0.f, 0.f, 0.f};
    #pragma unroll
    for (int kc = 0; kc < 128; kc += 32) {
        bf16x8 af[4], bfr[4];
        #pragma unroll
        for (int mr = 0; mr < 4; ++mr)
            af[mr] = *(const bf16x8*)&hbL[(rowbase + mr * 16 + l15) * 136 + kc + kg * 8];
        #pragma unroll
        for (int nr = 0; nr < 4; ++nr)
            bfr[nr] = *(const bf16x8*)&Wtcat[(size_t)(colbase + nr * 16 + l15) * 128 + kc + kg * 8];
        #pragma unroll
        for (int mr = 0; mr < 4; ++mr)
            #pragma unroll
            for (int nr = 0; nr < 4; ++nr)
                acc[mr][nr] = __builtin_amdgcn_mfma_f32_16x16x32_bf16(
                    af[mr], bfr[nr], acc[mr][nr], 0, 0, 0);
    }
    #pragma unroll
    for (int mr = 0; mr < 4; ++mr) {
        #pragma unroll
        for (int nr = 0; nr < 4; ++nr) {
            int col = colbase + nr * 16 + l15;
            float bv = (col >= 64) ? b2[col - 64] : 0.f;
            #pragma unroll
            for (int j = 0; j < 4; ++j) {
                int row = row0 + rowbase + mr * 16 + r4 + j;
                if (row < NN) {
                    float v = acc[mr][nr][j] + bv;
                    unsigned short bv16 = f2bf(v);
                    if (col < 64) g[(size_t)row * 64 + col] = bv16;
                    else          z[(size_t)row * 64 + (col - 64)] = bv16;
                }
            }
        }
    }
}

// ---------------- fused layer-2 tail: out = log_softmax(mean(g) + z) ----------------
__global__ __launch_bounds__(256)
void k_agg_lsm(const unsigned short* __restrict__ gbuf, const unsigned short* __restrict__ zbuf,
               const int* __restrict__ csr, const int* __restrict__ offs,
               const int* __restrict__ deg, float* __restrict__ out) {
    const int wid = threadIdx.x >> 6, lane = threadIdx.x & 63;
    const int g8 = lane >> 3, l8 = lane & 7;
    const int node = blockIdx.x * 4 + wid;
    if (node >= NN) return;
    int off = __builtin_amdgcn_readfirstlane(offs[node]);
    int dg  = __builtin_amdgcn_readfirstlane(deg[node]);
    const ush8* __restrict__ f8 = (const ush8*)gbuf;
    float acc[8];
    #pragma unroll
    for (int i = 0; i < 8; ++i) acc[i] = 0.f;
    int j = 0;
    for (; j + 32 <= dg; j += 32) {
        int e0 = csr[off + j + g8];
        int e1 = csr[off + j + 8 + g8];
        int e2 = csr[off + j + 16 + g8];
        int e3 = csr[off + j + 24 + g8];
        ush8 v0 = f8[(size_t)e0 * 8 + l8];
        ush8 v1 = f8[(size_t)e1 * 8 + l8];
        ush8 v2 = f8[(size_t)e2 * 8 + l8];
        ush8 v3 = f8[(size_t)e3 * 8 + l8];
        #pragma unroll
        for (int i = 0; i < 8; ++i)
            acc[i] += (b2f(v0[i]) + b2f(v1[i])) + (b2f(v2[i]) + b2f(v3[i]));
    }
    for (; j + 16 <= dg; j += 16) {
        int e0 = csr[off + j + g8];
        int e1 = csr[off + j + 8 + g8];
        ush8 v0 = f8[(size_t)e0 * 8 + l8];
        ush8 v1 = f8[(size_t)e1 * 8 + l8];
        #pragma unroll
        for (int i = 0; i < 8; ++i) acc[i] += b2f(v0[i]) + b2f(v1[i]);
    }
    for (; j + 8 <= dg; j += 8) {
        int e0 = csr[off + j + g8];
        ush8 v0 = f8[(size_t)e0 * 8 + l8];
        #pragma unroll
        for (int i = 0; i < 8; ++i) acc[i] += b2f(v0[i]);
    }
    int rem = dg - j;
    if (g8 < rem) {
        int e0 = csr[off + j + g8];
        ush8 v0 = f8[(size_t)e0 * 8 + l8];
        #pragma unroll
        for (int i = 0; i < 8; ++i) acc[i] += b2f(v0[i]);
    }
    #pragma unroll
    for (int i = 0; i < 8; ++i) {
        acc[i] += __shfl_xor(acc[i], 8);
        acc[i] += __shfl_xor(acc[i], 16);
        acc[i] += __shfl_xor(acc[i], 32);
    }
    float inv = 1.0f / (float)(dg > 0 ? dg : 1);
    ush8 zv = ((const ush8*)zbuf)[(size_t)node * 8 + l8];
    float v[8];
    float m = -1e30f;
    #pragma unroll
    for (int i = 0; i < 8; ++i) {
        v[i] = acc[i] * inv + b2f(zv[i]);
        m = fmaxf(m, v[i]);
    }
    #pragma unroll
    for (int d = 4; d >= 1; d >>= 1) m = fmaxf(m, __shfl_xor(m, d));
    float ss = 0.f;
    #pragma unroll
    for (int i = 0; i < 8; ++i) ss += __expf(v[i] - m);
    #pragma unroll
    for (int d = 4; d >= 1; d >>= 1) ss += __shfl_xor(ss, d);
    float lse = m + logf(ss);
    if (g8 == 0) {
        float4 o0 = make_float4(v[0] - lse, v[1] - lse, v[2] - lse, v[3] - lse);
        float4 o1 = make_float4(v[4] - lse, v[5] - lse, v[6] - lse, v[7] - lse);
        *(float4*)&out[(size_t)node * 64 + l8 * 8]     = o0;
        *(float4*)&out[(size_t)node * 64 + l8 * 8 + 4] = o1;
    }
}

// ---------------- launch ----------------
extern "C" void kernel_launch(void* const* d_in, const int* in_sizes, int n_in,
                              void* d_out, int out_size, void* d_ws, size_t ws_size,
                              hipStream_t stream) {
    const float* x   = (const float*)d_in[0];
    const int* edges = (const int*)d_in[1];
    const float* W1l = (const float*)d_in[2];
    const float* b1  = (const float*)d_in[3];
    const float* W1r = (const float*)d_in[4];
    const float* W2l = (const float*)d_in[5];
    const float* b2  = (const float*)d_in[6];
    const float* W2r = (const float*)d_in[7];
    float* out = (float*)d_out;

    const int* src = edges;            // edge_index[0]
    const int* dst = edges + NE;       // edge_index[1]

    char* ws = (char*)d_ws;
    size_t o = 0;
    auto alloc = [&](size_t bytes) -> void* {
        void* p = ws + o;
        o = (o + bytes + 255) & ~(size_t)255;
        return p;
    };
    int* gcnt  = (int*)alloc((size_t)NSB * 4);
    int* pairs = (int*)alloc((size_t)NSB * SBCAP * 4);   // becomes CSR after sortB
    int* offs  = (int*)alloc((size_t)NN * 4);
    int* deg   = (int*)alloc((size_t)NN * 4);
    unsigned short* xb    = (unsigned short*)alloc((size_t)NN * 128 * 2);
    unsigned short* meanb = (unsigned short*)alloc((size_t)NN * 128 * 2);
    unsigned short* gbuf  = (unsigned short*)alloc((size_t)NN * 64 * 2);
    unsigned short* zbuf  = (unsigned short*)alloc((size_t)NN * 64 * 2);
    unsigned short* Wt1l  = (unsigned short*)alloc(128 * 128 * 2);
    unsigned short* Wt1r  = (unsigned short*)alloc(128 * 128 * 2);
    unsigned short* Wtcat = (unsigned short*)alloc(128 * 128 * 2);

    hipMemsetAsync(gcnt, 0, (size_t)NSB * 4, stream);

    // conversions
    k_cvt_x<<<2048, 256, 0, stream>>>(x, xb, (long)NN * 128 / 8);
    k_cvt_weights<<<(3 * 16384 + 255) / 256, 256, 0, stream>>>(W1l, W1r, W2l, W2r,
                                                               Wt1l, Wt1r, Wtcat);

    // CSR build: two-level LDS counting sort
    k_binA<<<NBA, 1024, 0, stream>>>(src, dst, gcnt, pairs);
    k_sortB<<<NSB, 1024, 0, stream>>>(gcnt, pairs, offs, deg);

    const int GEMM_GRID = (NN + 127) / 128;   // 782
    // layer 1 aggregation
    k_aggregate_bf<<<(NN + 3) / 4, 256, 0, stream>>>(xb, pairs, offs, deg, meanb);
    // fused layer-1 GEMM + layer-2 cat GEMM (hb stays in LDS)
    k_gemm12<<<GEMM_GRID, 256, 0, stream>>>(meanb, xb, Wt1l, Wt1r, Wtcat, b1, b2, gbuf, zbuf);
    // layer-2 tail: fused 64-wide gather-mean + add + log_softmax
    k_agg_lsm<<<(NN + 3) / 4, 256, 0, stream>>>(gbuf, zbuf, pairs, offs, deg, out);
}

// Round 15
// 203.717 us; speedup vs baseline: 1.6196x; 1.0081x over previous
//
#include <hip/hip_runtime.h>
#include <hip/hip_fp8.h>
#include <math.h>

#define NN 100000
#define NE 1600000
#define SBN 512                      // nodes per super-bucket
#define NSB ((NN + SBN - 1) / SBN)   // 196 super-buckets
#define SBCAP 10240                  // per-super-bucket edge capacity (mean 8192)
#define EPB 8192                     // edges per binA block
#define NBA ((NE + EPB - 1) / EPB)   // 196 binA blocks

typedef __attribute__((ext_vector_type(8))) short bf16x8;   // 8 bf16 = 4 VGPR (MFMA A/B frag)
typedef __attribute__((ext_vector_type(8))) unsigned short ush8;
typedef __attribute__((ext_vector_type(4))) float f32x4;    // MFMA C/D frag

static __device__ __forceinline__ float b2f(unsigned short u) {
    return __uint_as_float(((unsigned int)u) << 16);
}
static __device__ __forceinline__ unsigned short f2bf(float f) {
    unsigned int u = __float_as_uint(f);
    u += 0x7fffu + ((u >> 16) & 1u);   // RNE
    return (unsigned short)(u >> 16);
}
static __device__ __forceinline__ unsigned char f2fp8(float f) {
    __hip_fp8_e4m3 q(f);
    return (unsigned char)q.__x;
}
// accumulate 4 fp8 (one u32) into acc[0..3]
static __device__ __forceinline__ void fp8x4_acc(unsigned int w, float* acc) {
#if __has_builtin(__builtin_amdgcn_cvt_pk_f32_fp8)
    auto lo = __builtin_amdgcn_cvt_pk_f32_fp8(w, false);
    auto hi = __builtin_amdgcn_cvt_pk_f32_fp8(w, true);
    acc[0] += lo[0]; acc[1] += lo[1]; acc[2] += hi[0]; acc[3] += hi[1];
#else
    #pragma unroll
    for (int k = 0; k < 4; ++k) {
        __hip_fp8_e4m3 q; q.__x = (__hip_fp8_storage_t)((w >> (8 * k)) & 0xffu);
        acc[k] += (float)q;
    }
#endif
}

// ---------------- conversions ----------------
// x f32 -> xb bf16 (for GEMM A-side) AND xq fp8 (for layer-1 gather)
__global__ __launch_bounds__(256)
void k_cvt_x(const float* __restrict__ in, unsigned short* __restrict__ outb,
             unsigned char* __restrict__ outq, long total8) {
    long i = (long)blockIdx.x * 256 + threadIdx.x;
    long stride = (long)gridDim.x * 256;
    for (; i < total8; i += stride) {
        const float4* p = (const float4*)(in + i * 8);
        float4 a = p[0], b = p[1];
        ush8 r;
        r[0] = f2bf(a.x); r[1] = f2bf(a.y); r[2] = f2bf(a.z); r[3] = f2bf(a.w);
        r[4] = f2bf(b.x); r[5] = f2bf(b.y); r[6] = f2bf(b.z); r[7] = f2bf(b.w);
        *(ush8*)(outb + i * 8) = r;
        unsigned int q0 = (unsigned int)f2fp8(a.x) | ((unsigned int)f2fp8(a.y) << 8) |
                          ((unsigned int)f2fp8(a.z) << 16) | ((unsigned int)f2fp8(a.w) << 24);
        unsigned int q1 = (unsigned int)f2fp8(b.x) | ((unsigned int)f2fp8(b.y) << 8) |
                          ((unsigned int)f2fp8(b.z) << 16) | ((unsigned int)f2fp8(b.w) << 24);
        *(uint2*)(outq + i * 8) = make_uint2(q0, q1);
    }
}

// all weights in one launch:
//   seg 0: Wt1l[n][k] = W1l[k][n]   (128x128)
//   seg 1: Wt1r[n][k] = W1r[k][n]   (128x128)
//   seg 2: Wtcat[n][k] = n<64 ? W2l[k][n] : W2r[k][n-64]
__global__ __launch_bounds__(256)
void k_cvt_weights(const float* __restrict__ W1l, const float* __restrict__ W1r,
                   const float* __restrict__ W2l, const float* __restrict__ W2r,
                   unsigned short* __restrict__ Wt1l, unsigned short* __restrict__ Wt1r,
                   unsigned short* __restrict__ Wtcat) {
    int id = blockIdx.x * 256 + threadIdx.x;
    int seg = id >> 14;              // 16384 elements per segment
    int e = id & 16383;
    int n = e >> 7, k = e & 127;
    if (seg == 0)      Wt1l[e] = f2bf(W1l[k * 128 + n]);
    else if (seg == 1) Wt1r[e] = f2bf(W1r[k * 128 + n]);
    else if (seg == 2) {
        float v = (n < 64) ? W2l[k * 64 + n] : W2r[k * 64 + (n - 64)];
        Wtcat[e] = f2bf(v);
    }
}

// ---------------- pass A: LDS-binned counting sort into 196 super-buckets ----------------
__global__ __launch_bounds__(1024)
void k_binA(const int* __restrict__ src, const int* __restrict__ dst,
            int* __restrict__ gcnt, int* __restrict__ pairs) {
    __shared__ int lsort[EPB];        // 32 KB
    __shared__ int lhist[256];
    __shared__ int lofs[256];         // exclusive offsets (immutable copy)
    __shared__ int lpos[NSB];
    __shared__ int gbase[NSB];
    const int tid = threadIdx.x;
    const int base = blockIdx.x * EPB;
    const int cnt = min(EPB, NE - base);

    int v[8], bn[8];
    #pragma unroll
    for (int k = 0; k < 8; ++k) {
        int i = k * 1024 + tid;
        if (i < cnt) {
            int d = dst[base + i], s = src[base + i];
            v[k] = (s << 9) | (d & 511);
            bn[k] = d >> 9;
        } else bn[k] = -1;
    }
    if (tid < 256) lhist[tid] = 0;
    __syncthreads();
    #pragma unroll
    for (int k = 0; k < 8; ++k) if (bn[k] >= 0) atomicAdd(&lhist[bn[k]], 1);
    __syncthreads();
    if (tid < 256) lofs[tid] = lhist[tid];
    __syncthreads();
    for (int d = 1; d < 256; d <<= 1) {
        int u = (tid < 256 && tid >= d) ? lofs[tid - d] : 0;
        __syncthreads();
        if (tid < 256) lofs[tid] += u;
        __syncthreads();
    }
    if (tid < 256) lofs[tid] -= lhist[tid];   // inclusive -> exclusive
    __syncthreads();
    if (tid < NSB) {
        lpos[tid] = lofs[tid];
        gbase[tid] = atomicAdd(&gcnt[tid], lhist[tid]);
    }
    __syncthreads();
    #pragma unroll
    for (int k = 0; k < 8; ++k) if (bn[k] >= 0) {
        int slot = atomicAdd(&lpos[bn[k]], 1);
        lsort[slot] = v[k];
    }
    __syncthreads();
    for (int i = tid; i < cnt; i += 1024) {
        int lo = 0, hi = NSB - 1;
        while (lo < hi) { int mid = (lo + hi + 1) >> 1; if (lofs[mid] <= i) lo = mid; else hi = mid - 1; }
        int off = gbase[lo] + (i - lofs[lo]);
        if (off < SBCAP)
            __builtin_nontemporal_store(lsort[i], &pairs[(size_t)lo * SBCAP + off]);
    }
}

// ---------------- pass B: per-super-bucket sort -> CSR (in place), deg/offs ----------------
__global__ __launch_bounds__(1024)
void k_sortB(const int* __restrict__ gcnt, int* __restrict__ pairs,
             int* __restrict__ offs, int* __restrict__ deg) {
    __shared__ int lstage[SBCAP];     // 40 KB
    __shared__ int lhist[SBN], lscan[SBN], lpos[SBN];
    const int sb = blockIdx.x, tid = threadIdx.x;
    const int cnt = min(gcnt[sb], SBCAP);
    int* __restrict__ region = pairs + (size_t)sb * SBCAP;

    for (int i = tid; i < cnt; i += 1024) lstage[i] = region[i];
    if (tid < SBN) lhist[tid] = 0;
    __syncthreads();
    for (int i = tid; i < cnt; i += 1024) atomicAdd(&lhist[lstage[i] & 511], 1);
    __syncthreads();
    if (tid < SBN) lscan[tid] = lhist[tid];
    __syncthreads();
    for (int d = 1; d < SBN; d <<= 1) {
        int u = (tid < SBN && tid >= d) ? lscan[tid - d] : 0;
        __syncthreads();
        if (tid < SBN) lscan[tid] += u;
        __syncthreads();
    }
    if (tid < SBN) {
        int ex = lscan[tid] - lhist[tid];
        lpos[tid] = ex;
        int node = sb * SBN + tid;
        if (node < NN) { offs[node] = sb * SBCAP + ex; deg[node] = lhist[tid]; }
    }
    __syncthreads();
    for (int i = tid; i < cnt; i += 1024) {
        int val = lstage[i];
        int slot = atomicAdd(&lpos[val & 511], 1);
        region[slot] = val >> 9;
    }
}

// ---------------- fp8 mean aggregation (layer 1): 8-lane groups, 8 edges/instr ----------------
// Row = 128 fp8 = 128B = 8 lanes x 16B. Output meanb bf16 (feeds MFMA GEMM).
__global__ __launch_bounds__(256)
void k_aggregate_f8(const unsigned char* __restrict__ featq, const int* __restrict__ csr,
                    const int* __restrict__ offs, const int* __restrict__ deg,
                    unsigned short* __restrict__ outmean) {
    const int wid = threadIdx.x >> 6, lane = threadIdx.x & 63;
    const int g8 = lane >> 3, l8 = lane & 7;
    const int node = blockIdx.x * 4 + wid;
    if (node >= NN) return;
    int off = __builtin_amdgcn_readfirstlane(offs[node]);
    int dg  = __builtin_amdgcn_readfirstlane(deg[node]);
    const uint4* __restrict__ f16b = (const uint4*)featq;   // 16 fp8 per uint4
    float acc[16];
    #pragma unroll
    for (int i = 0; i < 16; ++i) acc[i] = 0.f;
    int j = 0;
    for (; j + 16 <= dg; j += 16) {
        int e0 = csr[off + j + g8];
        int e1 = csr[off + j + 8 + g8];
        uint4 v0 = f16b[(size_t)e0 * 8 + l8];
        uint4 v1 = f16b[(size_t)e1 * 8 + l8];
        fp8x4_acc(v0.x, acc); fp8x4_acc(v0.y, acc + 4);
        fp8x4_acc(v0.z, acc + 8); fp8x4_acc(v0.w, acc + 12);
        fp8x4_acc(v1.x, acc); fp8x4_acc(v1.y, acc + 4);
        fp8x4_acc(v1.z, acc + 8); fp8x4_acc(v1.w, acc + 12);
    }
    for (; j + 8 <= dg; j += 8) {
        int e0 = csr[off + j + g8];
        uint4 v0 = f16b[(size_t)e0 * 8 + l8];
        fp8x4_acc(v0.x, acc); fp8x4_acc(v0.y, acc + 4);
        fp8x4_acc(v0.z, acc + 8); fp8x4_acc(v0.w, acc + 12);
    }
    int rem = dg - j;
    if (g8 < rem) {
        int e0 = csr[off + j + g8];
        uint4 v0 = f16b[(size_t)e0 * 8 + l8];
        fp8x4_acc(v0.x, acc); fp8x4_acc(v0.y, acc + 4);
        fp8x4_acc(v0.z, acc + 8); fp8x4_acc(v0.w, acc + 12);
    }
    #pragma unroll
    for (int i = 0; i < 16; ++i) {
        acc[i] += __shfl_xor(acc[i], 8);
        acc[i] += __shfl_xor(acc[i], 16);
        acc[i] += __shfl_xor(acc[i], 32);
    }
    if (g8 == 0) {
        float inv = 1.0f / (float)(dg > 0 ? dg : 1);
        ush8 r0, r1;
        #pragma unroll
        for (int i = 0; i < 8; ++i) { r0[i] = f2bf(acc[i] * inv); r1[i] = f2bf(acc[i + 8] * inv); }
        ((ush8*)outmean)[(size_t)node * 16 + l8 * 2]     = r0;
        ((ush8*)outmean)[(size_t)node * 16 + l8 * 2 + 1] = r1;
    }
}

// ---------------- fused GEMM chain: hb = relu(Am@W1l + Ax@W1r + b1) [LDS tile],
//                  then {g | z} = hb @ Wtcat (+b2 on z half). hb never hits HBM. ----------------
__global__ __launch_bounds__(256)
void k_gemm12(const unsigned short* __restrict__ Am, const unsigned short* __restrict__ Ax,
              const unsigned short* __restrict__ Wtl, const unsigned short* __restrict__ Wtr,
              const unsigned short* __restrict__ Wtcat,
              const float* __restrict__ b1, const float* __restrict__ b2,
              unsigned short* __restrict__ g, unsigned short* __restrict__ z) {
    // LDS union: phase A uses As[128*40] + Ws[128*40] (20,480 B);
    // after a barrier the same memory holds hbL[128][136] (34,816 B).
    __shared__ __align__(16) short lds[17408];
    short* As = lds;
    short* Ws = lds + 5120;
    short* hbL = lds;

    const int tid = threadIdx.x;
    const int wave = tid >> 6, lane = tid & 63;
    const int l15 = lane & 15, kg = lane >> 4;
    const int wc = wave & 1, wr = wave >> 1;
    const int rowbase = wr * 64;
    const int colbase = wc * 64;
    const int row0 = blockIdx.x * 128;
    const int r4 = kg * 4;

    f32x4 acc[4][4];
    #pragma unroll
    for (int mr = 0; mr < 4; ++mr)
        #pragma unroll
        for (int nr = 0; nr < 4; ++nr) acc[mr][nr] = (f32x4){0.f, 0.f, 0.f, 0.f};

    // ---- phase A: dual GEMM over meanb (Am) and xb (Ax) ----
    for (int s = 0; s < 2; ++s) {
        const unsigned short* __restrict__ A  = s ? Ax : Am;
        const unsigned short* __restrict__ Wt = s ? Wtr : Wtl;
        for (int kc = 0; kc < 128; kc += 32) {
            __syncthreads();
            #pragma unroll
            for (int i = 0; i < 2; ++i) {
                int c = tid + 256 * i; int r = c >> 2, gq = c & 3;
                ush8 v = {0, 0, 0, 0, 0, 0, 0, 0};
                int grow = row0 + r;
                if (grow < NN) v = *(const ush8*)&A[(size_t)grow * 128 + kc + gq * 8];
                *(ush8*)&As[r * 40 + gq * 8] = v;
            }
            #pragma unroll
            for (int i = 0; i < 2; ++i) {
                int c = tid + 256 * i; int n = c >> 2, gq = c & 3;
                *(ush8*)&Ws[n * 40 + gq * 8] = *(const ush8*)&Wt[n * 128 + kc + gq * 8];
            }
            __syncthreads();
            bf16x8 af[4], bfr[4];
            #pragma unroll
            for (int mr = 0; mr < 4; ++mr)
                af[mr] = *(const bf16x8*)&As[(rowbase + mr * 16 + l15) * 40 + kg * 8];
            #pragma unroll
            for (int nr = 0; nr < 4; ++nr)
                bfr[nr] = *(const bf16x8*)&Ws[(colbase + nr * 16 + l15) * 40 + kg * 8];
            #pragma unroll
            for (int mr = 0; mr < 4; ++mr)
                #pragma unroll
                for (int nr = 0; nr < 4; ++nr)
                    acc[mr][nr] = __builtin_amdgcn_mfma_f32_16x16x32_bf16(
                        af[mr], bfr[nr], acc[mr][nr], 0, 0, 0);
        }
    }

    // ---- write hb tile (relu + b1, bf16) into LDS union ----
    __syncthreads();   // all As/Ws reads complete before overwrite
    #pragma unroll
    for (int nr = 0; nr < 4; ++nr) {
        int col = colbase + nr * 16 + l15;
        float bv = b1[col];
        #pragma unroll
        for (int mr = 0; mr < 4; ++mr) {
            #pragma unroll
            for (int j = 0; j < 4; ++j) {
                int rl = rowbase + mr * 16 + r4 + j;
                float v = fmaxf(acc[mr][nr][j] + bv, 0.f);
                hbL[rl * 136 + col] = (short)f2bf(v);
            }
        }
    }
    __syncthreads();

    // ---- phase B: {g|z} = hbL @ Wtcat, K = 128, B direct from L1-resident global ----
    #pragma unroll
    for (int mr = 0; mr < 4; ++mr)
        #pragma unroll
        for (int nr = 0; nr < 4; ++nr) acc[mr][nr] = (f32x4){0.f, 0.f, 0.f, 0.f};
    #pragma unroll
    for (int kc = 0; kc < 128; kc += 32) {
        bf16x8 af[4], bfr[4];
        #pragma unroll
        for (int mr = 0; mr < 4; ++mr)
            af[mr] = *(const bf16x8*)&hbL[(rowbase + mr * 16 + l15) * 136 + kc + kg * 8];
        #pragma unroll
        for (int nr = 0; nr < 4; ++nr)
            bfr[nr] = *(const bf16x8*)&Wtcat[(size_t)(colbase + nr * 16 + l15) * 128 + kc + kg * 8];
        #pragma unroll
        for (int mr = 0; mr < 4; ++mr)
            #pragma unroll
            for (int nr = 0; nr < 4; ++nr)
                acc[mr][nr] = __builtin_amdgcn_mfma_f32_16x16x32_bf16(
                    af[mr], bfr[nr], acc[mr][nr], 0, 0, 0);
    }
    #pragma unroll
    for (int mr = 0; mr < 4; ++mr) {
        #pragma unroll
        for (int nr = 0; nr < 4; ++nr) {
            int col = colbase + nr * 16 + l15;
            float bv = (col >= 64) ? b2[col - 64] : 0.f;
            #pragma unroll
            for (int j = 0; j < 4; ++j) {
                int row = row0 + rowbase + mr * 16 + r4 + j;
                if (row < NN) {
                    float v = acc[mr][nr][j] + bv;
                    unsigned short bv16 = f2bf(v);
                    if (col < 64) g[(size_t)row * 64 + col] = bv16;
                    else          z[(size_t)row * 64 + (col - 64)] = bv16;
                }
            }
        }
    }
}

// ---------------- fused layer-2 tail: out = log_softmax(mean(g) + z), bf16 gather ----------------
__global__ __launch_bounds__(256)
void k_agg_lsm(const unsigned short* __restrict__ gbuf, const unsigned short* __restrict__ zbuf,
               const int* __restrict__ csr, const int* __restrict__ offs,
               const int* __restrict__ deg, float* __restrict__ out) {
    const int wid = threadIdx.x >> 6, lane = threadIdx.x & 63;
    const int g8 = lane >> 3, l8 = lane & 7;
    const int node = blockIdx.x * 4 + wid;
    if (node >= NN) return;
    int off = __builtin_amdgcn_readfirstlane(offs[node]);
    int dg  = __builtin_amdgcn_readfirstlane(deg[node]);
    const ush8* __restrict__ f8 = (const ush8*)gbuf;
    float acc[8];
    #pragma unroll
    for (int i = 0; i < 8; ++i) acc[i] = 0.f;
    int j = 0;
    for (; j + 32 <= dg; j += 32) {
        int e0 = csr[off + j + g8];
        int e1 = csr[off + j + 8 + g8];
        int e2 = csr[off + j + 16 + g8];
        int e3 = csr[off + j + 24 + g8];
        ush8 v0 = f8[(size_t)e0 * 8 + l8];
        ush8 v1 = f8[(size_t)e1 * 8 + l8];
        ush8 v2 = f8[(size_t)e2 * 8 + l8];
        ush8 v3 = f8[(size_t)e3 * 8 + l8];
        #pragma unroll
        for (int i = 0; i < 8; ++i)
            acc[i] += (b2f(v0[i]) + b2f(v1[i])) + (b2f(v2[i]) + b2f(v3[i]));
    }
    for (; j + 16 <= dg; j += 16) {
        int e0 = csr[off + j + g8];
        int e1 = csr[off + j + 8 + g8];
        ush8 v0 = f8[(size_t)e0 * 8 + l8];
        ush8 v1 = f8[(size_t)e1 * 8 + l8];
        #pragma unroll
        for (int i = 0; i < 8; ++i) acc[i] += b2f(v0[i]) + b2f(v1[i]);
    }
    for (; j + 8 <= dg; j += 8) {
        int e0 = csr[off + j + g8];
        ush8 v0 = f8[(size_t)e0 * 8 + l8];
        #pragma unroll
        for (int i = 0; i < 8; ++i) acc[i] += b2f(v0[i]);
    }
    int rem = dg - j;
    if (g8 < rem) {
        int e0 = csr[off + j + g8];
        ush8 v0 = f8[(size_t)e0 * 8 + l8];
        #pragma unroll
        for (int i = 0; i < 8; ++i) acc[i] += b2f(v0[i]);
    }
    #pragma unroll
    for (int i = 0; i < 8; ++i) {
        acc[i] += __shfl_xor(acc[i], 8);
        acc[i] += __shfl_xor(acc[i], 16);
        acc[i] += __shfl_xor(acc[i], 32);
    }
    float inv = 1.0f / (float)(dg > 0 ? dg : 1);
    ush8 zv = ((const ush8*)zbuf)[(size_t)node * 8 + l8];
    float v[8];
    float m = -1e30f;
    #pragma unroll
    for (int i = 0; i < 8; ++i) {
        v[i] = acc[i] * inv + b2f(zv[i]);
        m = fmaxf(m, v[i]);
    }
    #pragma unroll
    for (int d = 4; d >= 1; d >>= 1) m = fmaxf(m, __shfl_xor(m, d));
    float ss = 0.f;
    #pragma unroll
    for (int i = 0; i < 8; ++i) ss += __expf(v[i] - m);
    #pragma unroll
    for (int d = 4; d >= 1; d >>= 1) ss += __shfl_xor(ss, d);
    float lse = m + logf(ss);
    if (g8 == 0) {
        float4 o0 = make_float4(v[0] - lse, v[1] - lse, v[2] - lse, v[3] - lse);
        float4 o1 = make_float4(v[4] - lse, v[5] - lse, v[6] - lse, v[7] - lse);
        *(float4*)&out[(size_t)node * 64 + l8 * 8]     = o0;
        *(float4*)&out[(size_t)node * 64 + l8 * 8 + 4] = o1;
    }
}

// ---------------- launch ----------------
extern "C" void kernel_launch(void* const* d_in, const int* in_sizes, int n_in,
                              void* d_out, int out_size, void* d_ws, size_t ws_size,
                              hipStream_t stream) {
    const float* x   = (const float*)d_in[0];
    const int* edges = (const int*)d_in[1];
    const float* W1l = (const float*)d_in[2];
    const float* b1  = (const float*)d_in[3];
    const float* W1r = (const float*)d_in[4];
    const float* W2l = (const float*)d_in[5];
    const float* b2  = (const float*)d_in[6];
    const float* W2r = (const float*)d_in[7];
    float* out = (float*)d_out;

    const int* src = edges;            // edge_index[0]
    const int* dst = edges + NE;       // edge_index[1]

    char* ws = (char*)d_ws;
    size_t o = 0;
    auto alloc = [&](size_t bytes) -> void* {
        void* p = ws + o;
        o = (o + bytes + 255) & ~(size_t)255;
        return p;
    };
    int* gcnt  = (int*)alloc((size_t)NSB * 4);
    int* pairs = (int*)alloc((size_t)NSB * SBCAP * 4);   // becomes CSR after sortB
    int* offs  = (int*)alloc((size_t)NN * 4);
    int* deg   = (int*)alloc((size_t)NN * 4);
    unsigned short* xb    = (unsigned short*)alloc((size_t)NN * 128 * 2);
    unsigned char*  xq    = (unsigned char*)alloc((size_t)NN * 128);
    unsigned short* meanb = (unsigned short*)alloc((size_t)NN * 128 * 2);
    unsigned short* gbuf  = (unsigned short*)alloc((size_t)NN * 64 * 2);
    unsigned short* zbuf  = (unsigned short*)alloc((size_t)NN * 64 * 2);
    unsigned short* Wt1l  = (unsigned short*)alloc(128 * 128 * 2);
    unsigned short* Wt1r  = (unsigned short*)alloc(128 * 128 * 2);
    unsigned short* Wtcat = (unsigned short*)alloc(128 * 128 * 2);

    hipMemsetAsync(gcnt, 0, (size_t)NSB * 4, stream);

    // conversions
    k_cvt_x<<<2048, 256, 0, stream>>>(x, xb, xq, (long)NN * 128 / 8);
    k_cvt_weights<<<(3 * 16384 + 255) / 256, 256, 0, stream>>>(W1l, W1r, W2l, W2r,
                                                               Wt1l, Wt1r, Wtcat);

    // CSR build: two-level LDS counting sort
    k_binA<<<NBA, 1024, 0, stream>>>(src, dst, gcnt, pairs);
    k_sortB<<<NSB, 1024, 0, stream>>>(gcnt, pairs, offs, deg);

    const int GEMM_GRID = (NN + 127) / 128;   // 782
    // layer 1 aggregation: fp8 gather (128B rows) -> bf16 mean
    k_aggregate_f8<<<(NN + 3) / 4, 256, 0, stream>>>(xq, pairs, offs, deg, meanb);
    // fused layer-1 GEMM + layer-2 cat GEMM (hb stays in LDS)
    k_gemm12<<<GEMM_GRID, 256, 0, stream>>>(meanb, xb, Wt1l, Wt1r, Wtcat, b1, b2, gbuf, zbuf);
    // layer-2 tail: fused 64-wide gather-mean + add + log_softmax (bf16)
    k_agg_lsm<<<(NN + 3) / 4, 256, 0, stream>>>(gbuf, zbuf, pairs, offs, deg, out);
}